// Round 5
// baseline (191.930 us; speedup 1.0000x reference)
//
#include <hip/hip_runtime.h>

#define SN 5
#define BB 2048
#define KK 128
#define DD 64
#define H1 256
#define H2 128

// ws layout (floats):
//   stds:  [0, 66049)   std_w1|std_w2|std_w3|std_b1|std_b2|std_b3
//   x:     [66112, +1310720)   x[b][s][k]
//   h1:    [1376832, +2621440) h1[b][s][o]
//   h2:    aliases x (x dead after layer1)
// total ~16.0 MB — requires ws_size >= 16 MB.
#define OFF_W1 0
#define OFF_W2 32768
#define OFF_W3 65536
#define OFF_B1 65664
#define OFF_B2 65920
#define OFF_B3 66048
#define N_STD  66049
#define X_OFF  66112
#define H1_OFF (X_OFF + BB * SN * KK)
#define H2_OFF X_OFF

__device__ __forceinline__ float sp_(float x) {
  return (x > 20.f) ? x : log1pf(__expf(x));
}
__device__ __forceinline__ float sig_(float x) { return 1.f / (1.f + __expf(-x)); }
__device__ __forceinline__ float tanh_fast(float x) {
  float e = __expf(2.f * x);
  return 1.f - 2.f / (e + 1.f);
}
__device__ __forceinline__ float4 exp4_(float4 m, float4 s, float4 e) {
  float4 r;
  r.x = __expf(m.x + s.x * e.x);
  r.y = __expf(m.y + s.y * e.y);
  r.z = __expf(m.z + s.z * e.z);
  r.w = __expf(m.w + s.w * e.w);
  return r;
}
__device__ __forceinline__ float dot4_(float4 a, float4 b) {
  return a.x * b.x + a.y * b.y + a.z * b.z + a.w * b.w;
}

__global__ __launch_bounds__(256) void prep_kl(
    const float* w_mu1, const float* eta_w1, const float* b_mu1, const float* eta_b1,
    const float* w_mu2, const float* eta_w2, const float* b_mu2, const float* eta_b2,
    const float* w_mu3, const float* eta_w3, const float* b_mu3, const float* eta_b3,
    float* stds, float* kl_out)
{
  int f = blockIdx.x * 256 + threadIdx.x;
  float kle = 0.f;
  const float* mu = nullptr; const float* eta = nullptr; float* so = nullptr; int off = 0;
  if      (f < 32768) { mu = w_mu1; eta = eta_w1; so = stds + OFF_W1; off = f; }
  else if (f < 65536) { mu = w_mu2; eta = eta_w2; so = stds + OFF_W2; off = f - 32768; }
  else if (f < 65664) { mu = w_mu3; eta = eta_w3; so = stds + OFF_W3; off = f - 65536; }
  else if (f < 65920) { mu = b_mu1; eta = eta_b1; so = stds + OFF_B1; off = f - 65664; }
  else if (f < 66048) { mu = b_mu2; eta = eta_b2; so = stds + OFF_B2; off = f - 65920; }
  else if (f < 66049) { mu = b_mu3; eta = eta_b3; so = stds + OFF_B3; off = 0; }
  if (mu) {
    float s = 1e-6f + sp_(eta[off]);
    so[off] = s;
    float m = mu[off];
    kle = -logf(s) + 0.5f * (s * s + m * m - 1.0f);
  }
  __shared__ float red[256];
  red[threadIdx.x] = kle;
  __syncthreads();
  for (int w = 128; w > 0; w >>= 1) {
    if (threadIdx.x < w) red[threadIdx.x] += red[threadIdx.x + w];
    __syncthreads();
  }
  if (threadIdx.x == 0) atomicAdd(kl_out, red[0]);
}

__global__ __launch_bounds__(256) void x_kernel(
    const int* __restrict__ stu_id, const int* __restrict__ exer_id,
    const float* __restrict__ kn_r,
    const float* __restrict__ stu_cnt, const float* __restrict__ exer_cnt,
    const float* __restrict__ s_emb, const float* __restrict__ e_emb,
    const float* __restrict__ k_emb,
    const float* __restrict__ e_disc_mean, const float* __restrict__ e_disc_eta,
    const float* __restrict__ w_sm, const float* __restrict__ b_sm,
    const float* __restrict__ w_ss, const float* __restrict__ b_ss,
    const float* __restrict__ w_km, const float* __restrict__ b_km,
    const float* __restrict__ w_ks, const float* __restrict__ b_ks,
    const float* __restrict__ lam1s, const float* __restrict__ lam2s,
    const float* __restrict__ lam1e, const float* __restrict__ lam2e,
    const float* __restrict__ eps_stat, const float* __restrict__ eps_kdiff,
    const float* __restrict__ eps_disc,
    float* __restrict__ xout)
{
  const int b = blockIdx.x;
  const int t = threadIdx.x;

  __shared__ float su[DD], ee[DD];
  __shared__ float wsm[DD], wss[DD], wkm[DD], wks[DD];
  __shared__ float smean[KK], sstd[KK], kmean[KK], kstd[KK];
  __shared__ float discs[8];

  const int stu = stu_id[b], ex = exer_id[b];

  if (t < DD) {
    su[t] = s_emb[(size_t)stu * DD + t];
    wsm[t] = w_sm[t]; wss[t] = w_ss[t];
  } else if (t < 2 * DD) {
    int d = t - DD;
    ee[d] = e_emb[(size_t)ex * DD + d];
    wkm[d] = w_km[d]; wks[d] = w_ks[d];
  }
  if (t < SN) {
    float de = sp_(e_disc_eta[ex]);
    discs[t] = sig_(e_disc_mean[ex] + de * eps_disc[(size_t)t * BB + b]);
  }
  __syncthreads();

  if (t < KK) {
    const int k = t;
    float am = 0.f, as = 0.f;
    const float* kr = k_emb + (size_t)k * DD;
    #pragma unroll 8
    for (int d = 0; d < DD; ++d) { float p = su[d] * kr[d]; am += p * wsm[d]; as += p * wss[d]; }
    float sdata = sp_(lam1s[0]) * __expf(-sp_(lam2s[0]) * stu_cnt[stu]);
    smean[k] = am + b_sm[0];
    sstd[k]  = sdata + sp_(as + b_ss[0]);
  } else {
    const int k = t - KK;
    float am = 0.f, as = 0.f;
    const float* kr = k_emb + (size_t)k * DD;
    #pragma unroll 8
    for (int d = 0; d < DD; ++d) { float p = ee[d] * kr[d]; am += p * wkm[d]; as += p * wks[d]; }
    float edata = sp_(lam1e[0]) * __expf(-sp_(lam2e[0]) * exer_cnt[ex]);
    kmean[k] = am + b_km[0];
    kstd[k]  = edata + sp_(as + b_ks[0]);
  }
  __syncthreads();

  if (t < KK) {
    const int k = t;
    float knr = kn_r[(size_t)b * KK + k];
    float sm = smean[k], ss = sstd[k], km = kmean[k], ks = kstd[k];
    #pragma unroll
    for (int s = 0; s < SN; ++s) {
      float es = eps_stat [((size_t)s * BB + b) * KK + k];
      float ek = eps_kdiff[((size_t)s * BB + b) * KK + k];
      float st = sig_(sm + ss * es);
      float kd = sig_(km + ks * ek);
      xout[((size_t)b * SN + s) * KK + k] = discs[s] * (st - kd) * knr;
    }
  }
}

// one 16-lane group per output row; chunk-major grid: bi = chunk*BB + b
__global__ __launch_bounds__(256) void layer1_kernel(
    const float* __restrict__ w_mu1, const float* __restrict__ b_mu1,
    const float* __restrict__ eps_w1, const float* __restrict__ eps_b1,
    const float* __restrict__ stds, const float* __restrict__ x,
    float* __restrict__ h1)
{
  const int bi = blockIdx.x;
  const int b = bi & (BB - 1);
  const int chunk = bi >> 11;            // 0..15
  const int t = threadIdx.x, g = t >> 4, l16 = t & 15;
  const int o = chunk * 16 + g;

  __shared__ __align__(16) float xls[SN][KK];

  const float4* ep = (const float4*)(eps_w1 + ((size_t)b * H1 + o) * KK);
  const float4* mp = (const float4*)(w_mu1 + (size_t)o * KK);
  const float4* sq = (const float4*)(stds + OFF_W1 + (size_t)o * KK);
  float4 e0 = ep[l16], e1 = ep[l16 + 16];
  float4 m0 = mp[l16], m1 = mp[l16 + 16];
  float4 s0 = sq[l16], s1 = sq[l16 + 16];
  float bv = b_mu1[o] + stds[OFF_B1 + o] * eps_b1[(size_t)b * H1 + o];

  const float4* xsrc = (const float4*)(x + (size_t)b * (SN * KK));
  if (t < SN * KK / 4) ((float4*)&xls[0][0])[t] = xsrc[t];
  __syncthreads();

  float4 w0 = exp4_(m0, s0, e0);
  float4 w1 = exp4_(m1, s1, e1);
  #pragma unroll
  for (int s = 0; s < SN; ++s) {
    float4 xa = *(const float4*)&xls[s][l16 * 4];
    float4 xb = *(const float4*)&xls[s][64 + l16 * 4];
    float a = dot4_(w0, xa) + dot4_(w1, xb);
    a += __shfl_xor(a, 8);
    a += __shfl_xor(a, 4);
    a += __shfl_xor(a, 2);
    a += __shfl_xor(a, 1);
    if (l16 == 0) h1[((size_t)b * SN + s) * H1 + o] = tanh_fast(a + bv);
  }
}

__global__ __launch_bounds__(256) void layer2_kernel(
    const float* __restrict__ w_mu2, const float* __restrict__ b_mu2,
    const float* __restrict__ eps_w2, const float* __restrict__ eps_b2,
    const float* __restrict__ stds, const float* __restrict__ h1,
    float* __restrict__ h2)
{
  const int bi = blockIdx.x;
  const int b = bi & (BB - 1);
  const int chunk = bi >> 11;            // 0..7
  const int t = threadIdx.x, g = t >> 4, l16 = t & 15;
  const int o = chunk * 16 + g;

  __shared__ __align__(16) float hls[SN][H1];

  const float4* ep = (const float4*)(eps_w2 + ((size_t)b * H2 + o) * H1);
  const float4* mp = (const float4*)(w_mu2 + (size_t)o * H1);
  const float4* sq = (const float4*)(stds + OFF_W2 + (size_t)o * H1);
  float4 e0 = ep[l16], e1 = ep[l16 + 16], e2 = ep[l16 + 32], e3 = ep[l16 + 48];
  float4 m0 = mp[l16], m1 = mp[l16 + 16], m2 = mp[l16 + 32], m3 = mp[l16 + 48];
  float4 s0 = sq[l16], s1 = sq[l16 + 16], s2v = sq[l16 + 32], s3 = sq[l16 + 48];
  float bv = b_mu2[o] + stds[OFF_B2 + o] * eps_b2[(size_t)b * H2 + o];

  const float4* hsrc = (const float4*)(h1 + (size_t)b * (SN * H1));
  ((float4*)&hls[0][0])[t] = hsrc[t];
  if (t < SN * H1 / 4 - 256) ((float4*)&hls[0][0])[256 + t] = hsrc[256 + t];
  __syncthreads();

  float4 w0 = exp4_(m0, s0, e0);
  float4 w1 = exp4_(m1, s1, e1);
  float4 w2 = exp4_(m2, s2v, e2);
  float4 w3 = exp4_(m3, s3, e3);
  #pragma unroll
  for (int s = 0; s < SN; ++s) {
    float4 ha = *(const float4*)&hls[s][l16 * 4];
    float4 hb = *(const float4*)&hls[s][64 + l16 * 4];
    float4 hc = *(const float4*)&hls[s][128 + l16 * 4];
    float4 hd = *(const float4*)&hls[s][192 + l16 * 4];
    float a = dot4_(w0, ha) + dot4_(w1, hb) + dot4_(w2, hc) + dot4_(w3, hd);
    a += __shfl_xor(a, 8);
    a += __shfl_xor(a, 4);
    a += __shfl_xor(a, 2);
    a += __shfl_xor(a, 1);
    if (l16 == 0) h2[((size_t)b * SN + s) * H2 + o] = tanh_fast(a + bv);
  }
}

__global__ __launch_bounds__(256) void layer3_kernel(
    const float* __restrict__ w_mu3, const float* __restrict__ b_mu3,
    const float* __restrict__ eps_w3, const float* __restrict__ eps_b3,
    const float* __restrict__ stds, const float* __restrict__ h2,
    float* __restrict__ out)
{
  const int wv = threadIdx.x >> 6, l = threadIdx.x & 63;
  const int b = blockIdx.x * 4 + wv;
  float wa = __expf(w_mu3[l]      + stds[OFF_W3 + l]      * eps_w3[(size_t)b * H2 + l]);
  float wb = __expf(w_mu3[l + 64] + stds[OFF_W3 + l + 64] * eps_w3[(size_t)b * H2 + l + 64]);
  const float* hb = h2 + (size_t)b * SN * H2;
  float part[SN];
  #pragma unroll
  for (int s = 0; s < SN; ++s) part[s] = wa * hb[s * H2 + l] + wb * hb[s * H2 + l + 64];
  #pragma unroll
  for (int off = 32; off >= 1; off >>= 1) {
    #pragma unroll
    for (int s = 0; s < SN; ++s) part[s] += __shfl_xor(part[s], off);
  }
  if (l == 0) {
    float b3 = b_mu3[0] + stds[OFF_B3] * eps_b3[b];
    #pragma unroll
    for (int s = 0; s < SN; ++s) out[(size_t)s * BB + b] = sig_(part[s] + b3);
  }
}

extern "C" void kernel_launch(void* const* d_in, const int* in_sizes, int n_in,
                              void* d_out, int out_size, void* d_ws, size_t ws_size,
                              hipStream_t stream) {
  const int*   stu_id      = (const int*)  d_in[0];
  const int*   exer_id     = (const int*)  d_in[1];
  const float* kn_r        = (const float*)d_in[2];
  const float* stu_cnt     = (const float*)d_in[3];
  const float* exer_cnt    = (const float*)d_in[4];
  const float* s_emb       = (const float*)d_in[5];
  const float* e_emb       = (const float*)d_in[6];
  const float* k_emb       = (const float*)d_in[7];
  const float* e_disc_mean = (const float*)d_in[8];
  const float* e_disc_eta  = (const float*)d_in[9];
  const float* w_sm        = (const float*)d_in[10];
  const float* b_sm        = (const float*)d_in[11];
  const float* w_ss        = (const float*)d_in[12];
  const float* b_ss        = (const float*)d_in[13];
  const float* w_km        = (const float*)d_in[14];
  const float* b_km        = (const float*)d_in[15];
  const float* w_ks        = (const float*)d_in[16];
  const float* b_ks        = (const float*)d_in[17];
  const float* lam1s       = (const float*)d_in[18];
  const float* lam2s       = (const float*)d_in[19];
  const float* lam1e       = (const float*)d_in[20];
  const float* lam2e       = (const float*)d_in[21];
  const float* w_mu1       = (const float*)d_in[22];
  const float* eta_w1      = (const float*)d_in[23];
  const float* b_mu1       = (const float*)d_in[24];
  const float* eta_b1      = (const float*)d_in[25];
  const float* w_mu2       = (const float*)d_in[26];
  const float* eta_w2      = (const float*)d_in[27];
  const float* b_mu2       = (const float*)d_in[28];
  const float* eta_b2      = (const float*)d_in[29];
  const float* w_mu3       = (const float*)d_in[30];
  const float* eta_w3      = (const float*)d_in[31];
  const float* b_mu3       = (const float*)d_in[32];
  const float* eta_b3      = (const float*)d_in[33];
  const float* eps_stat    = (const float*)d_in[34];
  const float* eps_kdiff   = (const float*)d_in[35];
  const float* eps_disc    = (const float*)d_in[36];
  const float* eps_w1      = (const float*)d_in[37];
  const float* eps_b1      = (const float*)d_in[38];
  const float* eps_w2      = (const float*)d_in[39];
  const float* eps_b2      = (const float*)d_in[40];
  const float* eps_w3      = (const float*)d_in[41];
  const float* eps_b3      = (const float*)d_in[42];

  float* out  = (float*)d_out;
  float* ws   = (float*)d_ws;
  float* stds = ws;
  float* x    = ws + X_OFF;
  float* h1   = ws + H1_OFF;
  float* h2   = ws + H2_OFF;   // aliases x (x dead after layer1)

  hipMemsetAsync((char*)d_out + (size_t)SN * BB * sizeof(float), 0, sizeof(float), stream);

  prep_kl<<<(N_STD + 255) / 256, 256, 0, stream>>>(
      w_mu1, eta_w1, b_mu1, eta_b1,
      w_mu2, eta_w2, b_mu2, eta_b2,
      w_mu3, eta_w3, b_mu3, eta_b3,
      stds, out + (size_t)SN * BB);

  x_kernel<<<BB, 256, 0, stream>>>(
      stu_id, exer_id, kn_r, stu_cnt, exer_cnt,
      s_emb, e_emb, k_emb, e_disc_mean, e_disc_eta,
      w_sm, b_sm, w_ss, b_ss, w_km, b_km, w_ks, b_ks,
      lam1s, lam2s, lam1e, lam2e,
      eps_stat, eps_kdiff, eps_disc, x);

  layer1_kernel<<<16 * BB, 256, 0, stream>>>(
      w_mu1, b_mu1, eps_w1, eps_b1, stds, x, h1);

  layer2_kernel<<<8 * BB, 256, 0, stream>>>(
      w_mu2, b_mu2, eps_w2, eps_b2, stds, h1, h2);

  layer3_kernel<<<BB / 4, 256, 0, stream>>>(
      w_mu3, b_mu3, eps_w3, eps_b3, stds, h2, out);
}

// Round 6
// 174.904 us; speedup vs baseline: 1.0973x; 1.0973x over previous
//
#include <hip/hip_runtime.h>

#define SN 5
#define BB 2048
#define KK 128
#define DD 64
#define H1 256
#define H2 128

// ws layout (floats):
//   stds:  [0, 66049)
//   x:     [66112, +1310720)   x[b][s][k]
//   h1:    [1376832, +2621440) h1[b][s][o]
//   h2:    aliases x (x dead after layer1)
#define OFF_W1 0
#define OFF_W2 32768
#define OFF_W3 65536
#define OFF_B1 65664
#define OFF_B2 65920
#define OFF_B3 66048
#define N_STD  66049
#define X_OFF  66112
#define H1_OFF (X_OFF + BB * SN * KK)
#define H2_OFF X_OFF

__device__ __forceinline__ float sp_(float x) {
  return (x > 20.f) ? x : log1pf(__expf(x));
}
__device__ __forceinline__ float sig_(float x) { return 1.f / (1.f + __expf(-x)); }
__device__ __forceinline__ float tanh_fast(float x) {
  float e = __expf(2.f * x);
  return 1.f - 2.f / (e + 1.f);
}
__device__ __forceinline__ float4 exp4_(float4 m, float4 s, float4 e) {
  float4 r;
  r.x = __expf(m.x + s.x * e.x);
  r.y = __expf(m.y + s.y * e.y);
  r.z = __expf(m.z + s.z * e.z);
  r.w = __expf(m.w + s.w * e.w);
  return r;
}
__device__ __forceinline__ float dot4_(float4 a, float4 b) {
  return a.x * b.x + a.y * b.y + a.z * b.z + a.w * b.w;
}

__global__ __launch_bounds__(256) void prep_kl(
    const float* w_mu1, const float* eta_w1, const float* b_mu1, const float* eta_b1,
    const float* w_mu2, const float* eta_w2, const float* b_mu2, const float* eta_b2,
    const float* w_mu3, const float* eta_w3, const float* b_mu3, const float* eta_b3,
    float* stds, float* kl_out)
{
  int f = blockIdx.x * 256 + threadIdx.x;
  float kle = 0.f;
  const float* mu = nullptr; const float* eta = nullptr; float* so = nullptr; int off = 0;
  if      (f < 32768) { mu = w_mu1; eta = eta_w1; so = stds + OFF_W1; off = f; }
  else if (f < 65536) { mu = w_mu2; eta = eta_w2; so = stds + OFF_W2; off = f - 32768; }
  else if (f < 65664) { mu = w_mu3; eta = eta_w3; so = stds + OFF_W3; off = f - 65536; }
  else if (f < 65920) { mu = b_mu1; eta = eta_b1; so = stds + OFF_B1; off = f - 65664; }
  else if (f < 66048) { mu = b_mu2; eta = eta_b2; so = stds + OFF_B2; off = f - 65920; }
  else if (f < 66049) { mu = b_mu3; eta = eta_b3; so = stds + OFF_B3; off = 0; }
  if (mu) {
    float s = 1e-6f + sp_(eta[off]);
    so[off] = s;
    float m = mu[off];
    kle = -logf(s) + 0.5f * (s * s + m * m - 1.0f);
  }
  __shared__ float red[256];
  red[threadIdx.x] = kle;
  __syncthreads();
  for (int w = 128; w > 0; w >>= 1) {
    if (threadIdx.x < w) red[threadIdx.x] += red[threadIdx.x + w];
    __syncthreads();
  }
  if (threadIdx.x == 0) atomicAdd(kl_out, red[0]);
}

__global__ __launch_bounds__(256) void x_kernel(
    const int* __restrict__ stu_id, const int* __restrict__ exer_id,
    const float* __restrict__ kn_r,
    const float* __restrict__ stu_cnt, const float* __restrict__ exer_cnt,
    const float* __restrict__ s_emb, const float* __restrict__ e_emb,
    const float* __restrict__ k_emb,
    const float* __restrict__ e_disc_mean, const float* __restrict__ e_disc_eta,
    const float* __restrict__ w_sm, const float* __restrict__ b_sm,
    const float* __restrict__ w_ss, const float* __restrict__ b_ss,
    const float* __restrict__ w_km, const float* __restrict__ b_km,
    const float* __restrict__ w_ks, const float* __restrict__ b_ks,
    const float* __restrict__ lam1s, const float* __restrict__ lam2s,
    const float* __restrict__ lam1e, const float* __restrict__ lam2e,
    const float* __restrict__ eps_stat, const float* __restrict__ eps_kdiff,
    const float* __restrict__ eps_disc,
    float* __restrict__ xout)
{
  const int b = blockIdx.x;
  const int t = threadIdx.x;

  __shared__ float su[DD], ee[DD];
  __shared__ float wsm[DD], wss[DD], wkm[DD], wks[DD];
  __shared__ float smean[KK], sstd[KK], kmean[KK], kstd[KK];
  __shared__ float discs[8];

  const int stu = stu_id[b], ex = exer_id[b];

  if (t < DD) {
    su[t] = s_emb[(size_t)stu * DD + t];
    wsm[t] = w_sm[t]; wss[t] = w_ss[t];
  } else if (t < 2 * DD) {
    int d = t - DD;
    ee[d] = e_emb[(size_t)ex * DD + d];
    wkm[d] = w_km[d]; wks[d] = w_ks[d];
  }
  if (t < SN) {
    float de = sp_(e_disc_eta[ex]);
    discs[t] = sig_(e_disc_mean[ex] + de * eps_disc[(size_t)t * BB + b]);
  }
  __syncthreads();

  if (t < KK) {
    const int k = t;
    float am = 0.f, as = 0.f;
    const float* kr = k_emb + (size_t)k * DD;
    #pragma unroll 8
    for (int d = 0; d < DD; ++d) { float p = su[d] * kr[d]; am += p * wsm[d]; as += p * wss[d]; }
    float sdata = sp_(lam1s[0]) * __expf(-sp_(lam2s[0]) * stu_cnt[stu]);
    smean[k] = am + b_sm[0];
    sstd[k]  = sdata + sp_(as + b_ss[0]);
  } else {
    const int k = t - KK;
    float am = 0.f, as = 0.f;
    const float* kr = k_emb + (size_t)k * DD;
    #pragma unroll 8
    for (int d = 0; d < DD; ++d) { float p = ee[d] * kr[d]; am += p * wkm[d]; as += p * wks[d]; }
    float edata = sp_(lam1e[0]) * __expf(-sp_(lam2e[0]) * exer_cnt[ex]);
    kmean[k] = am + b_km[0];
    kstd[k]  = edata + sp_(as + b_ks[0]);
  }
  __syncthreads();

  if (t < KK) {
    const int k = t;
    float knr = kn_r[(size_t)b * KK + k];
    float sm = smean[k], ss = sstd[k], km = kmean[k], ks = kstd[k];
    #pragma unroll
    for (int s = 0; s < SN; ++s) {
      float es = eps_stat [((size_t)s * BB + b) * KK + k];
      float ek = eps_kdiff[((size_t)s * BB + b) * KK + k];
      float st = sig_(sm + ss * es);
      float kd = sig_(km + ks * ek);
      xout[((size_t)b * SN + s) * KK + k] = discs[s] * (st - kd) * knr;
    }
  }
}

// block = 16 output rows (chunk) x 8 batch elements (btile).
// grid: 16 chunks * 256 btiles; btile-major so concurrent blocks share mu/std in L2.
__global__ __launch_bounds__(256) void layer1_kernel(
    const float* __restrict__ w_mu1, const float* __restrict__ b_mu1,
    const float* __restrict__ eps_w1, const float* __restrict__ eps_b1,
    const float* __restrict__ stds, const float* __restrict__ x,
    float* __restrict__ h1)
{
  const int bi = blockIdx.x;
  const int btile = bi & 255;
  const int chunk = bi >> 8;           // 0..15
  const int t = threadIdx.x, g = t >> 4, l16 = t & 15;
  const int o = chunk * 16 + g;
  const int b0 = btile * 8;

  __shared__ __align__(16) float xls[8][SN][KK];   // 20 KB

  // stage x for all 8 b's once (1280 float4, 5 rounds)
  const float4* xsrc = (const float4*)(x + (size_t)b0 * SN * KK);
  float4* xdst = (float4*)&xls[0][0][0];
  #pragma unroll
  for (int r = 0; r < 5; ++r) xdst[r * 256 + t] = xsrc[r * 256 + t];

  // per-row mu/std held in registers for all 8 b's
  const float4* mp = (const float4*)(w_mu1 + (size_t)o * KK);
  const float4* sq = (const float4*)(stds + OFF_W1 + (size_t)o * KK);
  float4 m0 = mp[l16], m1 = mp[l16 + 16];
  float4 s0 = sq[l16], s1 = sq[l16 + 16];
  float bmu = b_mu1[o], bsd = stds[OFF_B1 + o];

  const float4* ep = (const float4*)(eps_w1 + ((size_t)b0 * H1 + o) * KK) + l16;
  // b-stride in float4: H1*KK/4 = 8192
  float4 e0 = ep[0], e1 = ep[16];

  __syncthreads();

  #pragma unroll
  for (int ib = 0; ib < 8; ++ib) {
    float4 ce0 = e0, ce1 = e1;
    if (ib < 7) {
      e0 = ep[(size_t)(ib + 1) * 8192];
      e1 = ep[(size_t)(ib + 1) * 8192 + 16];
    }
    const int b = b0 + ib;
    float4 w0 = exp4_(m0, s0, ce0);
    float4 w1 = exp4_(m1, s1, ce1);
    float bv = bmu + bsd * eps_b1[(size_t)b * H1 + o];
    #pragma unroll
    for (int s = 0; s < SN; ++s) {
      float4 xa = *(const float4*)&xls[ib][s][l16 * 4];
      float4 xb = *(const float4*)&xls[ib][s][64 + l16 * 4];
      float a = dot4_(w0, xa) + dot4_(w1, xb);
      a += __shfl_xor(a, 8);
      a += __shfl_xor(a, 4);
      a += __shfl_xor(a, 2);
      a += __shfl_xor(a, 1);
      if (l16 == 0) h1[((size_t)b * SN + s) * H1 + o] = tanh_fast(a + bv);
    }
  }
}

// block = 16 output rows x 8 batch elements; grid: 8 chunks * 256 btiles.
__global__ __launch_bounds__(256) void layer2_kernel(
    const float* __restrict__ w_mu2, const float* __restrict__ b_mu2,
    const float* __restrict__ eps_w2, const float* __restrict__ eps_b2,
    const float* __restrict__ stds, const float* __restrict__ h1,
    float* __restrict__ h2)
{
  const int bi = blockIdx.x;
  const int btile = bi & 255;
  const int chunk = bi >> 8;           // 0..7
  const int t = threadIdx.x, g = t >> 4, l16 = t & 15;
  const int o = chunk * 16 + g;
  const int b0 = btile * 8;

  __shared__ __align__(16) float hls[8][SN][H1];   // 40 KB

  // stage h1 for all 8 b's once (2560 float4, 10 rounds)
  const float4* hsrc = (const float4*)(h1 + (size_t)b0 * SN * H1);
  float4* hdst = (float4*)&hls[0][0][0];
  #pragma unroll
  for (int r = 0; r < 10; ++r) hdst[r * 256 + t] = hsrc[r * 256 + t];

  const float4* mp = (const float4*)(w_mu2 + (size_t)o * H1);
  const float4* sq = (const float4*)(stds + OFF_W2 + (size_t)o * H1);
  float4 m0 = mp[l16], m1 = mp[l16 + 16], m2 = mp[l16 + 32], m3 = mp[l16 + 48];
  float4 s0 = sq[l16], s1 = sq[l16 + 16], s2v = sq[l16 + 32], s3 = sq[l16 + 48];
  float bmu = b_mu2[o], bsd = stds[OFF_B2 + o];

  const float4* ep = (const float4*)(eps_w2 + ((size_t)b0 * H2 + o) * H1) + l16;
  // b-stride in float4: H2*H1/4 = 8192
  float4 e0 = ep[0], e1 = ep[16], e2 = ep[32], e3 = ep[48];

  __syncthreads();

  #pragma unroll
  for (int ib = 0; ib < 8; ++ib) {
    float4 ce0 = e0, ce1 = e1, ce2 = e2, ce3 = e3;
    if (ib < 7) {
      size_t nb = (size_t)(ib + 1) * 8192;
      e0 = ep[nb]; e1 = ep[nb + 16]; e2 = ep[nb + 32]; e3 = ep[nb + 48];
    }
    const int b = b0 + ib;
    float4 w0 = exp4_(m0, s0, ce0);
    float4 w1 = exp4_(m1, s1, ce1);
    float4 w2 = exp4_(m2, s2v, ce2);
    float4 w3 = exp4_(m3, s3, ce3);
    float bv = bmu + bsd * eps_b2[(size_t)b * H2 + o];
    #pragma unroll
    for (int s = 0; s < SN; ++s) {
      float4 ha = *(const float4*)&hls[ib][s][l16 * 4];
      float4 hb = *(const float4*)&hls[ib][s][64 + l16 * 4];
      float4 hc = *(const float4*)&hls[ib][s][128 + l16 * 4];
      float4 hd = *(const float4*)&hls[ib][s][192 + l16 * 4];
      float a = dot4_(w0, ha) + dot4_(w1, hb) + dot4_(w2, hc) + dot4_(w3, hd);
      a += __shfl_xor(a, 8);
      a += __shfl_xor(a, 4);
      a += __shfl_xor(a, 2);
      a += __shfl_xor(a, 1);
      if (l16 == 0) h2[((size_t)b * SN + s) * H2 + o] = tanh_fast(a + bv);
    }
  }
}

__global__ __launch_bounds__(256) void layer3_kernel(
    const float* __restrict__ w_mu3, const float* __restrict__ b_mu3,
    const float* __restrict__ eps_w3, const float* __restrict__ eps_b3,
    const float* __restrict__ stds, const float* __restrict__ h2,
    float* __restrict__ out)
{
  const int wv = threadIdx.x >> 6, l = threadIdx.x & 63;
  const int b = blockIdx.x * 4 + wv;
  float wa = __expf(w_mu3[l]      + stds[OFF_W3 + l]      * eps_w3[(size_t)b * H2 + l]);
  float wb = __expf(w_mu3[l + 64] + stds[OFF_W3 + l + 64] * eps_w3[(size_t)b * H2 + l + 64]);
  const float* hb = h2 + (size_t)b * SN * H2;
  float part[SN];
  #pragma unroll
  for (int s = 0; s < SN; ++s) part[s] = wa * hb[s * H2 + l] + wb * hb[s * H2 + l + 64];
  #pragma unroll
  for (int off = 32; off >= 1; off >>= 1) {
    #pragma unroll
    for (int s = 0; s < SN; ++s) part[s] += __shfl_xor(part[s], off);
  }
  if (l == 0) {
    float b3 = b_mu3[0] + stds[OFF_B3] * eps_b3[b];
    #pragma unroll
    for (int s = 0; s < SN; ++s) out[(size_t)s * BB + b] = sig_(part[s] + b3);
  }
}

extern "C" void kernel_launch(void* const* d_in, const int* in_sizes, int n_in,
                              void* d_out, int out_size, void* d_ws, size_t ws_size,
                              hipStream_t stream) {
  const int*   stu_id      = (const int*)  d_in[0];
  const int*   exer_id     = (const int*)  d_in[1];
  const float* kn_r        = (const float*)d_in[2];
  const float* stu_cnt     = (const float*)d_in[3];
  const float* exer_cnt    = (const float*)d_in[4];
  const float* s_emb       = (const float*)d_in[5];
  const float* e_emb       = (const float*)d_in[6];
  const float* k_emb       = (const float*)d_in[7];
  const float* e_disc_mean = (const float*)d_in[8];
  const float* e_disc_eta  = (const float*)d_in[9];
  const float* w_sm        = (const float*)d_in[10];
  const float* b_sm        = (const float*)d_in[11];
  const float* w_ss        = (const float*)d_in[12];
  const float* b_ss        = (const float*)d_in[13];
  const float* w_km        = (const float*)d_in[14];
  const float* b_km        = (const float*)d_in[15];
  const float* w_ks        = (const float*)d_in[16];
  const float* b_ks        = (const float*)d_in[17];
  const float* lam1s       = (const float*)d_in[18];
  const float* lam2s       = (const float*)d_in[19];
  const float* lam1e       = (const float*)d_in[20];
  const float* lam2e       = (const float*)d_in[21];
  const float* w_mu1       = (const float*)d_in[22];
  const float* eta_w1      = (const float*)d_in[23];
  const float* b_mu1       = (const float*)d_in[24];
  const float* eta_b1      = (const float*)d_in[25];
  const float* w_mu2       = (const float*)d_in[26];
  const float* eta_w2      = (const float*)d_in[27];
  const float* b_mu2       = (const float*)d_in[28];
  const float* eta_b2      = (const float*)d_in[29];
  const float* w_mu3       = (const float*)d_in[30];
  const float* eta_w3      = (const float*)d_in[31];
  const float* b_mu3       = (const float*)d_in[32];
  const float* eta_b3      = (const float*)d_in[33];
  const float* eps_stat    = (const float*)d_in[34];
  const float* eps_kdiff   = (const float*)d_in[35];
  const float* eps_disc    = (const float*)d_in[36];
  const float* eps_w1      = (const float*)d_in[37];
  const float* eps_b1      = (const float*)d_in[38];
  const float* eps_w2      = (const float*)d_in[39];
  const float* eps_b2      = (const float*)d_in[40];
  const float* eps_w3      = (const float*)d_in[41];
  const float* eps_b3      = (const float*)d_in[42];

  float* out  = (float*)d_out;
  float* ws   = (float*)d_ws;
  float* stds = ws;
  float* x    = ws + X_OFF;
  float* h1   = ws + H1_OFF;
  float* h2   = ws + H2_OFF;   // aliases x (x dead after layer1)

  hipMemsetAsync((char*)d_out + (size_t)SN * BB * sizeof(float), 0, sizeof(float), stream);

  prep_kl<<<(N_STD + 255) / 256, 256, 0, stream>>>(
      w_mu1, eta_w1, b_mu1, eta_b1,
      w_mu2, eta_w2, b_mu2, eta_b2,
      w_mu3, eta_w3, b_mu3, eta_b3,
      stds, out + (size_t)SN * BB);

  x_kernel<<<BB, 256, 0, stream>>>(
      stu_id, exer_id, kn_r, stu_cnt, exer_cnt,
      s_emb, e_emb, k_emb, e_disc_mean, e_disc_eta,
      w_sm, b_sm, w_ss, b_ss, w_km, b_km, w_ks, b_ks,
      lam1s, lam2s, lam1e, lam2e,
      eps_stat, eps_kdiff, eps_disc, x);

  layer1_kernel<<<16 * 256, 256, 0, stream>>>(
      w_mu1, b_mu1, eps_w1, eps_b1, stds, x, h1);

  layer2_kernel<<<8 * 256, 256, 0, stream>>>(
      w_mu2, b_mu2, eps_w2, eps_b2, stds, h1, h2);

  layer3_kernel<<<BB / 4, 256, 0, stream>>>(
      w_mu3, b_mu3, eps_w3, eps_b3, stds, h2, out);
}

// Round 7
// 159.489 us; speedup vs baseline: 1.2034x; 1.0967x over previous
//
#include <hip/hip_runtime.h>

#define SN 5
#define BB 2048
#define KK 128
#define DD 64
#define H1 256
#define H2 128

// ws float layout:
//   P1:  [0, 65536)        paired scaled w1: for pi in [0,8192): [8*pi..8*pi+3]=mu4*log2e, [8*pi+4..8*pi+7]=std4*log2e
//   P2:  [65536, 131072)   paired scaled w2 (same layout)
//   W3S: [131072, +128)    mu3*log2e
//   S3S: [131200, +128)    std3*log2e
//   SB1: [131328, +256)    std_b1 (raw)
//   SB2: [131584, +128)    std_b2 (raw)
//   SB3: [131712, +1)      std_b3 (raw)
#define P2F   65536
#define W3S   131072
#define S3S   131200
#define SB1F  131328
#define SB2F  131584
#define SB3F  131712
#define N_STD 66049

#define LOG2E 1.4426950408889634f

#if defined(__has_builtin)
#if __has_builtin(__builtin_amdgcn_exp2f)
#define EXP2(x) __builtin_amdgcn_exp2f(x)
#else
#define EXP2(x) __expf(0.6931471805599453f * (x))
#endif
#if __has_builtin(__builtin_amdgcn_rcpf)
#define RCP(x) __builtin_amdgcn_rcpf(x)
#else
#define RCP(x) (1.0f / (x))
#endif
#else
#define EXP2(x) __expf(0.6931471805599453f * (x))
#define RCP(x) (1.0f / (x))
#endif

__device__ __forceinline__ float sp_(float x) {
  return (x > 20.f) ? x : log1pf(__expf(x));
}
__device__ __forceinline__ float sig_(float x) { return RCP(1.f + __expf(-x)); }
__device__ __forceinline__ float tanh_fast(float x) {
  float e = EXP2(2.8853900817779268f * x);   // exp(2x)
  return 1.f - 2.f * RCP(e + 1.f);
}
// weights: w = exp(mu + std*eps) = exp2(mu' + std'*eps) with pre-scaled tables
__device__ __forceinline__ float4 exp2m4_(float4 m, float4 s, float4 e) {
  float4 r;
  r.x = EXP2(m.x + s.x * e.x);
  r.y = EXP2(m.y + s.y * e.y);
  r.z = EXP2(m.z + s.z * e.z);
  r.w = EXP2(m.w + s.w * e.w);
  return r;
}
__device__ __forceinline__ float dot4_(float4 a, float4 b) {
  return a.x * b.x + a.y * b.y + a.z * b.z + a.w * b.w;
}

__global__ __launch_bounds__(256) void prep_kl(
    const float* w_mu1, const float* eta_w1, const float* b_mu1, const float* eta_b1,
    const float* w_mu2, const float* eta_w2, const float* b_mu2, const float* eta_b2,
    const float* w_mu3, const float* eta_w3, const float* b_mu3, const float* eta_b3,
    float* ws, float* kl_out)
{
  int f = blockIdx.x * 256 + threadIdx.x;
  float kle = 0.f;
  if (f < N_STD) {
    float m, s;
    if (f < 32768) {
      m = w_mu1[f]; s = 1e-6f + sp_(eta_w1[f]);
      int pi = f >> 2, c = f & 3;
      ws[8 * pi + c]     = m * LOG2E;
      ws[8 * pi + 4 + c] = s * LOG2E;
    } else if (f < 65536) {
      int g = f - 32768;
      m = w_mu2[g]; s = 1e-6f + sp_(eta_w2[g]);
      int pi = g >> 2, c = g & 3;
      ws[P2F + 8 * pi + c]     = m * LOG2E;
      ws[P2F + 8 * pi + 4 + c] = s * LOG2E;
    } else if (f < 65664) {
      int i = f - 65536;
      m = w_mu3[i]; s = 1e-6f + sp_(eta_w3[i]);
      ws[W3S + i] = m * LOG2E;
      ws[S3S + i] = s * LOG2E;
    } else if (f < 65920) {
      int i = f - 65664;
      m = b_mu1[i]; s = 1e-6f + sp_(eta_b1[i]);
      ws[SB1F + i] = s;
    } else if (f < 66048) {
      int i = f - 65920;
      m = b_mu2[i]; s = 1e-6f + sp_(eta_b2[i]);
      ws[SB2F + i] = s;
    } else {
      m = b_mu3[0]; s = 1e-6f + sp_(eta_b3[0]);
      ws[SB3F] = s;
    }
    kle = -logf(s) + 0.5f * (s * s + m * m - 1.0f);
  }
  __shared__ float red[256];
  red[threadIdx.x] = kle;
  __syncthreads();
  for (int w = 128; w > 0; w >>= 1) {
    if (threadIdx.x < w) red[threadIdx.x] += red[threadIdx.x + w];
    __syncthreads();
  }
  if (threadIdx.x == 0) atomicAdd(kl_out, red[0]);
}

__global__ __launch_bounds__(256, 4) void bayes_main(
    const int* __restrict__ stu_id, const int* __restrict__ exer_id,
    const float* __restrict__ kn_r,
    const float* __restrict__ stu_cnt, const float* __restrict__ exer_cnt,
    const float* __restrict__ s_emb, const float* __restrict__ e_emb,
    const float* __restrict__ k_emb,
    const float* __restrict__ e_disc_mean, const float* __restrict__ e_disc_eta,
    const float* __restrict__ w_sm, const float* __restrict__ b_sm,
    const float* __restrict__ w_ss, const float* __restrict__ b_ss,
    const float* __restrict__ w_km, const float* __restrict__ b_km,
    const float* __restrict__ w_ks, const float* __restrict__ b_ks,
    const float* __restrict__ lam1s, const float* __restrict__ lam2s,
    const float* __restrict__ lam1e, const float* __restrict__ lam2e,
    const float* __restrict__ b_mu1, const float* __restrict__ b_mu2,
    const float* __restrict__ b_mu3,
    const float* __restrict__ eps_stat, const float* __restrict__ eps_kdiff,
    const float* __restrict__ eps_disc,
    const float* __restrict__ eps_w1, const float* __restrict__ eps_b1,
    const float* __restrict__ eps_w2, const float* __restrict__ eps_b2,
    const float* __restrict__ eps_w3, const float* __restrict__ eps_b3,
    const float* __restrict__ tabs,
    float* __restrict__ out)
{
  const int b = blockIdx.x;
  const int t = threadIdx.x;

  __shared__ float su[DD], ee[DD];
  __shared__ float wsm[DD], wss[DD], wkm[DD], wks[DD];
  __shared__ float smean[KK], sstd[KK], kmean[KK], kstd[KK];
  __shared__ float discs[8];
  __shared__ __align__(16) float xs[SN][KK];
  __shared__ __align__(16) float h1s[SN][H1];
  __shared__ __align__(16) float h2s[SN][H2];
  __shared__ float bias1[H1];
  __shared__ float bias2[H2];
  __shared__ float w3v[H2];

  const int stu = stu_id[b], ex = exer_id[b];

  // ---- phase 0: small gathers + per-b bias/w3 precompute ----
  if (t < DD) {
    su[t] = s_emb[(size_t)stu * DD + t];
    wsm[t] = w_sm[t]; wss[t] = w_ss[t];
  } else if (t < 2 * DD) {
    int d = t - DD;
    ee[d] = e_emb[(size_t)ex * DD + d];
    wkm[d] = w_km[d]; wks[d] = w_ks[d];
  }
  bias1[t] = b_mu1[t] + tabs[SB1F + t] * eps_b1[(size_t)b * H1 + t];
  if (t < H2) {
    bias2[t] = b_mu2[t] + tabs[SB2F + t] * eps_b2[(size_t)b * H2 + t];
    w3v[t] = EXP2(tabs[W3S + t] + tabs[S3S + t] * eps_w3[(size_t)b * H2 + t]);
  }
  if (t < SN) {
    float de = sp_(e_disc_eta[ex]);
    discs[t] = sig_(e_disc_mean[ex] + de * eps_disc[(size_t)t * BB + b]);
  }
  __syncthreads();

  // ---- phase 1: per-k stat/kdiff mean & std ----
  if (t < KK) {
    const int k = t;
    float am = 0.f, as = 0.f;
    const float* kr = k_emb + (size_t)k * DD;
    #pragma unroll 8
    for (int d = 0; d < DD; ++d) { float p = su[d] * kr[d]; am += p * wsm[d]; as += p * wss[d]; }
    float sdata = sp_(lam1s[0]) * __expf(-sp_(lam2s[0]) * stu_cnt[stu]);
    smean[k] = am + b_sm[0];
    sstd[k]  = sdata + sp_(as + b_ss[0]);
  } else {
    const int k = t - KK;
    float am = 0.f, as = 0.f;
    const float* kr = k_emb + (size_t)k * DD;
    #pragma unroll 8
    for (int d = 0; d < DD; ++d) { float p = ee[d] * kr[d]; am += p * wkm[d]; as += p * wks[d]; }
    float edata = sp_(lam1e[0]) * __expf(-sp_(lam2e[0]) * exer_cnt[ex]);
    kmean[k] = am + b_km[0];
    kstd[k]  = edata + sp_(as + b_ks[0]);
  }
  __syncthreads();

  // ---- phase 2: x[s][k] ----
  if (t < KK) {
    const int k = t;
    float knr = kn_r[(size_t)b * KK + k];
    float sm = smean[k], ss = sstd[k], km = kmean[k], ks = kstd[k];
    #pragma unroll
    for (int s = 0; s < SN; ++s) {
      float es = eps_stat [((size_t)s * BB + b) * KK + k];
      float ek = eps_kdiff[((size_t)s * BB + b) * KK + k];
      float st = sig_(sm + ss * es);
      float kd = sig_(km + ks * ek);
      xs[s][k] = discs[s] * (st - kd) * knr;
    }
  }
  __syncthreads();

  const int g = t >> 4, l16 = t & 15;

  // ---- phase 3: layer 1 — 2 rows per group per pass, paired scaled tables ----
  {
    const int lane1 = g * 32 + l16;  // f4 units
    const float4* ep = (const float4*)(eps_w1 + (size_t)b * H1 * KK) + lane1;
    const float4* tp = (const float4*)tabs + 2 * lane1;

    float4 eA0 = ep[0], eA1 = ep[16], eA2 = ep[512], eA3 = ep[528];
    float4 eB0, eB1, eB2, eB3;

    #pragma unroll
    for (int p = 0; p < 8; ++p) {
      const int B0 = p * 1024;
      const int C = 2 * B0;
      float4 ce0, ce1, ce2, ce3;
      if (p & 1) { ce0 = eB0; ce1 = eB1; ce2 = eB2; ce3 = eB3; }
      else       { ce0 = eA0; ce1 = eA1; ce2 = eA2; ce3 = eA3; }
      if (p < 7) {
        if (p & 1) {
          eA0 = ep[B0 + 1024]; eA1 = ep[B0 + 1040];
          eA2 = ep[B0 + 1536]; eA3 = ep[B0 + 1552];
        } else {
          eB0 = ep[B0 + 1024]; eB1 = ep[B0 + 1040];
          eB2 = ep[B0 + 1536]; eB3 = ep[B0 + 1552];
        }
      }
      float4 m0 = tp[C],        s0 = tp[C + 1];
      float4 m1 = tp[C + 32],   s1 = tp[C + 33];
      float4 m2 = tp[C + 1024], s2v = tp[C + 1025];
      float4 m3 = tp[C + 1056], s3 = tp[C + 1057];
      float4 wA0 = exp2m4_(m0, s0, ce0);
      float4 wA1 = exp2m4_(m1, s1, ce1);
      float4 wB0 = exp2m4_(m2, s2v, ce2);
      float4 wB1 = exp2m4_(m3, s3, ce3);

      float red[SN];
      #pragma unroll
      for (int s2 = 0; s2 < SN; ++s2) {
        float4 xa = *(const float4*)&xs[s2][l16 * 4];
        float4 xb = *(const float4*)&xs[s2][64 + l16 * 4];
        float a0 = dot4_(wA0, xa) + dot4_(wA1, xb);
        float a1 = dot4_(wB0, xa) + dot4_(wB1, xb);
        float u0 = __shfl_xor(a0, 8);
        float u1 = __shfl_xor(a1, 8);
        float a = (l16 < 8) ? (a0 + u0) : (a1 + u1);
        a += __shfl_xor(a, 4);
        a += __shfl_xor(a, 2);
        a += __shfl_xor(a, 1);
        red[s2] = a;
      }
      const int o0 = p * 32 + g, o1 = o0 + 16;
      if (l16 == 0) {
        #pragma unroll
        for (int s2 = 0; s2 < SN; ++s2) h1s[s2][o0] = tanh_fast(red[s2] + bias1[o0]);
      } else if (l16 == 8) {
        #pragma unroll
        for (int s2 = 0; s2 < SN; ++s2) h1s[s2][o1] = tanh_fast(red[s2] + bias1[o1]);
      }
    }
  }
  __syncthreads();

  // ---- phase 4: layer 2 — 2 rows per group per pass ----
  {
    const int lane2 = g * 64 + l16;  // f4 units
    const float4* ep = (const float4*)(eps_w2 + (size_t)b * H2 * H1) + lane2;
    const float4* tp = (const float4*)tabs + 2 * P2F / 4 / 2 * 2 + 2 * lane2;  // = tabs_f4 + P2F/4*2? computed below
    // P2F floats = P2F/4 float4s of mu+std pairs start; paired table occupies 2x floats
    // correct base: (const float4*)(tabs + P2F) + 2*lane2
    tp = (const float4*)(tabs + P2F) + 2 * lane2;

    float4 fA[8], fB[8];
    #pragma unroll
    for (int c = 0; c < 4; ++c) {
      fA[c]     = ep[c * 16];
      fA[4 + c] = ep[1024 + c * 16];
    }

    #pragma unroll
    for (int p = 0; p < 4; ++p) {
      const int B0 = p * 2048;
      const int C = 2 * B0;
      float4 cf[8];
      #pragma unroll
      for (int c = 0; c < 8; ++c) cf[c] = (p & 1) ? fB[c] : fA[c];
      if (p < 3) {
        #pragma unroll
        for (int c = 0; c < 4; ++c) {
          if (p & 1) {
            fA[c]     = ep[B0 + 2048 + c * 16];
            fA[4 + c] = ep[B0 + 3072 + c * 16];
          } else {
            fB[c]     = ep[B0 + 2048 + c * 16];
            fB[4 + c] = ep[B0 + 3072 + c * 16];
          }
        }
      }
      float a0[SN] = {0.f, 0.f, 0.f, 0.f, 0.f};
      float a1[SN] = {0.f, 0.f, 0.f, 0.f, 0.f};
      #pragma unroll
      for (int c = 0; c < 4; ++c) {
        float4 m0 = tp[C + c * 32],        s0 = tp[C + c * 32 + 1];
        float4 m1 = tp[C + 2048 + c * 32], s1 = tp[C + 2048 + c * 32 + 1];
        float4 w0 = exp2m4_(m0, s0, cf[c]);
        float4 w1 = exp2m4_(m1, s1, cf[4 + c]);
        #pragma unroll
        for (int s2 = 0; s2 < SN; ++s2) {
          float4 h = *(const float4*)&h1s[s2][c * 64 + l16 * 4];
          a0[s2] += dot4_(w0, h);
          a1[s2] += dot4_(w1, h);
        }
      }
      float red[SN];
      #pragma unroll
      for (int s2 = 0; s2 < SN; ++s2) {
        float u0 = __shfl_xor(a0[s2], 8);
        float u1 = __shfl_xor(a1[s2], 8);
        float a = (l16 < 8) ? (a0[s2] + u0) : (a1[s2] + u1);
        a += __shfl_xor(a, 4);
        a += __shfl_xor(a, 2);
        a += __shfl_xor(a, 1);
        red[s2] = a;
      }
      const int o0 = p * 32 + g, o1 = o0 + 16;
      if (l16 == 0) {
        #pragma unroll
        for (int s2 = 0; s2 < SN; ++s2) h2s[s2][o0] = tanh_fast(red[s2] + bias2[o0]);
      } else if (l16 == 8) {
        #pragma unroll
        for (int s2 = 0; s2 < SN; ++s2) h2s[s2][o1] = tanh_fast(red[s2] + bias2[o1]);
      }
    }
  }
  __syncthreads();

  // ---- phase 5: layer 3 + sigmoid, wave 0 only ----
  if (t < 64) {
    float w3a = w3v[t];
    float w3b = w3v[t + 64];
    float part[SN];
    #pragma unroll
    for (int s2 = 0; s2 < SN; ++s2) part[s2] = w3a * h2s[s2][t] + w3b * h2s[s2][t + 64];
    #pragma unroll
    for (int off = 32; off >= 1; off >>= 1) {
      #pragma unroll
      for (int s2 = 0; s2 < SN; ++s2) part[s2] += __shfl_xor(part[s2], off);
    }
    if (t == 0) {
      float bb3 = b_mu3[0] + tabs[SB3F] * eps_b3[b];
      #pragma unroll
      for (int s2 = 0; s2 < SN; ++s2) out[(size_t)s2 * BB + b] = sig_(part[s2] + bb3);
    }
  }
}

extern "C" void kernel_launch(void* const* d_in, const int* in_sizes, int n_in,
                              void* d_out, int out_size, void* d_ws, size_t ws_size,
                              hipStream_t stream) {
  const int*   stu_id      = (const int*)  d_in[0];
  const int*   exer_id     = (const int*)  d_in[1];
  const float* kn_r        = (const float*)d_in[2];
  const float* stu_cnt     = (const float*)d_in[3];
  const float* exer_cnt    = (const float*)d_in[4];
  const float* s_emb       = (const float*)d_in[5];
  const float* e_emb       = (const float*)d_in[6];
  const float* k_emb       = (const float*)d_in[7];
  const float* e_disc_mean = (const float*)d_in[8];
  const float* e_disc_eta  = (const float*)d_in[9];
  const float* w_sm        = (const float*)d_in[10];
  const float* b_sm        = (const float*)d_in[11];
  const float* w_ss        = (const float*)d_in[12];
  const float* b_ss        = (const float*)d_in[13];
  const float* w_km        = (const float*)d_in[14];
  const float* b_km        = (const float*)d_in[15];
  const float* w_ks        = (const float*)d_in[16];
  const float* b_ks        = (const float*)d_in[17];
  const float* lam1s       = (const float*)d_in[18];
  const float* lam2s       = (const float*)d_in[19];
  const float* lam1e       = (const float*)d_in[20];
  const float* lam2e       = (const float*)d_in[21];
  const float* w_mu1       = (const float*)d_in[22];
  const float* eta_w1      = (const float*)d_in[23];
  const float* b_mu1       = (const float*)d_in[24];
  const float* eta_b1      = (const float*)d_in[25];
  const float* w_mu2       = (const float*)d_in[26];
  const float* eta_w2      = (const float*)d_in[27];
  const float* b_mu2       = (const float*)d_in[28];
  const float* eta_b2      = (const float*)d_in[29];
  const float* w_mu3       = (const float*)d_in[30];
  const float* eta_w3      = (const float*)d_in[31];
  const float* b_mu3       = (const float*)d_in[32];
  const float* eta_b3      = (const float*)d_in[33];
  const float* eps_stat    = (const float*)d_in[34];
  const float* eps_kdiff   = (const float*)d_in[35];
  const float* eps_disc    = (const float*)d_in[36];
  const float* eps_w1      = (const float*)d_in[37];
  const float* eps_b1      = (const float*)d_in[38];
  const float* eps_w2      = (const float*)d_in[39];
  const float* eps_b2      = (const float*)d_in[40];
  const float* eps_w3      = (const float*)d_in[41];
  const float* eps_b3      = (const float*)d_in[42];

  float* out = (float*)d_out;
  float* ws  = (float*)d_ws;

  hipMemsetAsync((char*)d_out + (size_t)SN * BB * sizeof(float), 0, sizeof(float), stream);

  prep_kl<<<(N_STD + 255) / 256, 256, 0, stream>>>(
      w_mu1, eta_w1, b_mu1, eta_b1,
      w_mu2, eta_w2, b_mu2, eta_b2,
      w_mu3, eta_w3, b_mu3, eta_b3,
      ws, out + (size_t)SN * BB);

  bayes_main<<<BB, 256, 0, stream>>>(
      stu_id, exer_id, kn_r, stu_cnt, exer_cnt,
      s_emb, e_emb, k_emb, e_disc_mean, e_disc_eta,
      w_sm, b_sm, w_ss, b_ss, w_km, b_km, w_ks, b_ks,
      lam1s, lam2s, lam1e, lam2e,
      b_mu1, b_mu2, b_mu3,
      eps_stat, eps_kdiff, eps_disc,
      eps_w1, eps_b1, eps_w2, eps_b2, eps_w3, eps_b3,
      ws, out);
}

// Round 8
// 156.514 us; speedup vs baseline: 1.2263x; 1.0190x over previous
//
#include <hip/hip_runtime.h>

#define SN 5
#define BB 2048
#define KK 128
#define DD 64
#define H1 256
#define H2 128

// ws float layout:
//   P1:  [0, 65536)        paired scaled w1: for pi in [0,8192): [8*pi..+3]=mu4*log2e, [8*pi+4..+7]=std4*log2e
//   P2:  [65536, 131072)   paired scaled w2 (same layout)
//   W3S: [131072, +128)    mu3*log2e
//   S3S: [131200, +128)    std3*log2e
//   SB1: [131328, +256)    std_b1 (raw)
//   SB2: [131584, +128)    std_b2 (raw)
//   SB3: [131712, +1)      std_b3 (raw)
#define P2F   65536
#define W3S   131072
#define S3S   131200
#define SB1F  131328
#define SB2F  131584
#define SB3F  131712
#define N_STD 66049

#define LOG2E 1.4426950408889634f

#if defined(__has_builtin)
#if __has_builtin(__builtin_amdgcn_exp2f)
#define EXP2(x) __builtin_amdgcn_exp2f(x)
#else
#define EXP2(x) __expf(0.6931471805599453f * (x))
#endif
#if __has_builtin(__builtin_amdgcn_rcpf)
#define RCP(x) __builtin_amdgcn_rcpf(x)
#else
#define RCP(x) (1.0f / (x))
#endif
#else
#define EXP2(x) __expf(0.6931471805599453f * (x))
#define RCP(x) (1.0f / (x))
#endif

__device__ __forceinline__ void bar_lgkm() {
  // LDS-only barrier: do NOT drain vmcnt, so global prefetch survives.
  asm volatile("s_waitcnt lgkmcnt(0)\n\ts_barrier" ::: "memory");
}

__device__ __forceinline__ float sp_(float x) {
  return (x > 20.f) ? x : log1pf(__expf(x));
}
__device__ __forceinline__ float sig_(float x) { return RCP(1.f + __expf(-x)); }
__device__ __forceinline__ float tanh_fast(float x) {
  float e = EXP2(2.8853900817779268f * x);   // exp(2x)
  return 1.f - 2.f * RCP(e + 1.f);
}
__device__ __forceinline__ float4 exp2m4_(float4 m, float4 s, float4 e) {
  float4 r;
  r.x = EXP2(m.x + s.x * e.x);
  r.y = EXP2(m.y + s.y * e.y);
  r.z = EXP2(m.z + s.z * e.z);
  r.w = EXP2(m.w + s.w * e.w);
  return r;
}
__device__ __forceinline__ float dot4_(float4 a, float4 b) {
  return a.x * b.x + a.y * b.y + a.z * b.z + a.w * b.w;
}

__global__ __launch_bounds__(256) void prep_kl(
    const float* w_mu1, const float* eta_w1, const float* b_mu1, const float* eta_b1,
    const float* w_mu2, const float* eta_w2, const float* b_mu2, const float* eta_b2,
    const float* w_mu3, const float* eta_w3, const float* b_mu3, const float* eta_b3,
    float* ws, float* kl_out)
{
  int f = blockIdx.x * 256 + threadIdx.x;
  float kle = 0.f;
  if (f < N_STD) {
    float m, s;
    if (f < 32768) {
      m = w_mu1[f]; s = 1e-6f + sp_(eta_w1[f]);
      int pi = f >> 2, c = f & 3;
      ws[8 * pi + c]     = m * LOG2E;
      ws[8 * pi + 4 + c] = s * LOG2E;
    } else if (f < 65536) {
      int g = f - 32768;
      m = w_mu2[g]; s = 1e-6f + sp_(eta_w2[g]);
      int pi = g >> 2, c = g & 3;
      ws[P2F + 8 * pi + c]     = m * LOG2E;
      ws[P2F + 8 * pi + 4 + c] = s * LOG2E;
    } else if (f < 65664) {
      int i = f - 65536;
      m = w_mu3[i]; s = 1e-6f + sp_(eta_w3[i]);
      ws[W3S + i] = m * LOG2E;
      ws[S3S + i] = s * LOG2E;
    } else if (f < 65920) {
      int i = f - 65664;
      m = b_mu1[i]; s = 1e-6f + sp_(eta_b1[i]);
      ws[SB1F + i] = s;
    } else if (f < 66048) {
      int i = f - 65920;
      m = b_mu2[i]; s = 1e-6f + sp_(eta_b2[i]);
      ws[SB2F + i] = s;
    } else {
      m = b_mu3[0]; s = 1e-6f + sp_(eta_b3[0]);
      ws[SB3F] = s;
    }
    kle = -logf(s) + 0.5f * (s * s + m * m - 1.0f);
  }
  __shared__ float red[256];
  red[threadIdx.x] = kle;
  __syncthreads();
  for (int w = 128; w > 0; w >>= 1) {
    if (threadIdx.x < w) red[threadIdx.x] += red[threadIdx.x + w];
    __syncthreads();
  }
  if (threadIdx.x == 0) atomicAdd(kl_out, red[0]);
}

__global__ __launch_bounds__(256, 4) void bayes_main(
    const int* __restrict__ stu_id, const int* __restrict__ exer_id,
    const float* __restrict__ kn_r,
    const float* __restrict__ stu_cnt, const float* __restrict__ exer_cnt,
    const float* __restrict__ s_emb, const float* __restrict__ e_emb,
    const float* __restrict__ k_emb,
    const float* __restrict__ e_disc_mean, const float* __restrict__ e_disc_eta,
    const float* __restrict__ w_sm, const float* __restrict__ b_sm,
    const float* __restrict__ w_ss, const float* __restrict__ b_ss,
    const float* __restrict__ w_km, const float* __restrict__ b_km,
    const float* __restrict__ w_ks, const float* __restrict__ b_ks,
    const float* __restrict__ lam1s, const float* __restrict__ lam2s,
    const float* __restrict__ lam1e, const float* __restrict__ lam2e,
    const float* __restrict__ b_mu1, const float* __restrict__ b_mu2,
    const float* __restrict__ b_mu3,
    const float* __restrict__ eps_stat, const float* __restrict__ eps_kdiff,
    const float* __restrict__ eps_disc,
    const float* __restrict__ eps_w1, const float* __restrict__ eps_b1,
    const float* __restrict__ eps_w2, const float* __restrict__ eps_b2,
    const float* __restrict__ eps_w3, const float* __restrict__ eps_b3,
    const float* __restrict__ tabs,
    float* __restrict__ out)
{
  const int b = blockIdx.x;
  const int t = threadIdx.x;

  __shared__ float su[DD], ee[DD];
  __shared__ float wsm[DD], wss[DD], wkm[DD], wks[DD];
  __shared__ float smean[KK], sstd[KK], kmean[KK], kstd[KK];
  __shared__ float discs[8];
  __shared__ __align__(16) float xs[SN][KK];
  __shared__ __align__(16) float h1s[SN][H1];
  __shared__ __align__(16) float h2s[SN][H2];
  __shared__ float bias1[H1];
  __shared__ float bias2[H2];
  __shared__ float w3v[H2];

  const int stu = stu_id[b], ex = exer_id[b];
  const int g = t >> 4, l16 = t & 15;

  // ---- phase 0: small gathers + per-b bias/w3 precompute ----
  if (t < DD) {
    su[t] = s_emb[(size_t)stu * DD + t];
    wsm[t] = w_sm[t]; wss[t] = w_ss[t];
  } else if (t < 2 * DD) {
    int d = t - DD;
    ee[d] = e_emb[(size_t)ex * DD + d];
    wkm[d] = w_km[d]; wks[d] = w_ks[d];
  }
  bias1[t] = b_mu1[t] + tabs[SB1F + t] * eps_b1[(size_t)b * H1 + t];
  if (t < H2) {
    bias2[t] = b_mu2[t] + tabs[SB2F + t] * eps_b2[(size_t)b * H2 + t];
    w3v[t] = EXP2(tabs[W3S + t] + tabs[S3S + t] * eps_w3[(size_t)b * H2 + t]);
  }
  if (t < SN) {
    float de = sp_(e_disc_eta[ex]);
    discs[t] = sig_(e_disc_mean[ex] + de * eps_disc[(size_t)t * BB + b]);
  }
  bar_lgkm();

  // ---- phase 1: per-k stat/kdiff mean & std ----
  if (t < KK) {
    const int k = t;
    float am = 0.f, as = 0.f;
    const float* kr = k_emb + (size_t)k * DD;
    #pragma unroll 8
    for (int d = 0; d < DD; ++d) { float p = su[d] * kr[d]; am += p * wsm[d]; as += p * wss[d]; }
    float sdata = sp_(lam1s[0]) * __expf(-sp_(lam2s[0]) * stu_cnt[stu]);
    smean[k] = am + b_sm[0];
    sstd[k]  = sdata + sp_(as + b_ss[0]);
  } else {
    const int k = t - KK;
    float am = 0.f, as = 0.f;
    const float* kr = k_emb + (size_t)k * DD;
    #pragma unroll 8
    for (int d = 0; d < DD; ++d) { float p = ee[d] * kr[d]; am += p * wkm[d]; as += p * wks[d]; }
    float edata = sp_(lam1e[0]) * __expf(-sp_(lam2e[0]) * exer_cnt[ex]);
    kmean[k] = am + b_km[0];
    kstd[k]  = edata + sp_(as + b_ks[0]);
  }

  // hoisted issue: phase-2 eps scalars (arrive during barrier+phase-2 lead-in)
  float esv[SN], ekv[SN], knrv = 0.f;
  if (t < KK) {
    knrv = kn_r[(size_t)b * KK + t];
    #pragma unroll
    for (int s = 0; s < SN; ++s) {
      esv[s] = eps_stat [((size_t)s * BB + b) * KK + t];
      ekv[s] = eps_kdiff[((size_t)s * BB + b) * KK + t];
    }
  }

  // hoisted issue: layer-1 eps prologue (passes 0 and 1)
  const int lane1 = g * 32 + l16;  // f4 units
  const float4* ep1 = (const float4*)(eps_w1 + (size_t)b * H1 * KK) + lane1;
  float4 c0 = ep1[0],    c1 = ep1[16],   c2 = ep1[512],  c3 = ep1[528];
  float4 d0 = ep1[1024], d1 = ep1[1040], d2 = ep1[1536], d3 = ep1[1552];

  bar_lgkm();

  // ---- phase 2: x[s][k] ----
  if (t < KK) {
    const int k = t;
    float sm = smean[k], ss = sstd[k], km = kmean[k], ks = kstd[k];
    #pragma unroll
    for (int s = 0; s < SN; ++s) {
      float st = sig_(sm + ss * esv[s]);
      float kd = sig_(km + ks * ekv[s]);
      xs[s][k] = discs[s] * (st - kd) * knrv;
    }
  }
  bar_lgkm();

  // ---- phase 3: layer 1 — 2 rows/group/pass, depth-2 eps prefetch ----
  {
    const float4* tp = (const float4*)tabs + 2 * lane1;

    #pragma unroll
    for (int p = 0; p < 8; ++p) {
      const int B0 = p * 1024;
      const int C = 2 * B0;
      float4 n0, n1, n2, n3;
      if (p < 6) {
        n0 = ep1[B0 + 2048]; n1 = ep1[B0 + 2064];
        n2 = ep1[B0 + 2560]; n3 = ep1[B0 + 2576];
      }
      float4 m0 = tp[C],        s0 = tp[C + 1];
      float4 m1 = tp[C + 32],   s1 = tp[C + 33];
      float4 m2 = tp[C + 1024], s2v = tp[C + 1025];
      float4 m3 = tp[C + 1056], s3 = tp[C + 1057];
      float4 wA0 = exp2m4_(m0, s0, c0);
      float4 wA1 = exp2m4_(m1, s1, c1);
      float4 wB0 = exp2m4_(m2, s2v, c2);
      float4 wB1 = exp2m4_(m3, s3, c3);

      float red[SN];
      #pragma unroll
      for (int s2 = 0; s2 < SN; ++s2) {
        float4 xa = *(const float4*)&xs[s2][l16 * 4];
        float4 xb = *(const float4*)&xs[s2][64 + l16 * 4];
        float a0 = dot4_(wA0, xa) + dot4_(wA1, xb);
        float a1 = dot4_(wB0, xa) + dot4_(wB1, xb);
        float u0 = __shfl_xor(a0, 8);
        float u1 = __shfl_xor(a1, 8);
        float a = (l16 < 8) ? (a0 + u0) : (a1 + u1);
        a += __shfl_xor(a, 4);
        a += __shfl_xor(a, 2);
        a += __shfl_xor(a, 1);
        red[s2] = a;
      }
      const int o0 = p * 32 + g, o1 = o0 + 16;
      if (l16 == 0) {
        #pragma unroll
        for (int s2 = 0; s2 < SN; ++s2) h1s[s2][o0] = tanh_fast(red[s2] + bias1[o0]);
      } else if (l16 == 8) {
        #pragma unroll
        for (int s2 = 0; s2 < SN; ++s2) h1s[s2][o1] = tanh_fast(red[s2] + bias1[o1]);
      }
      // rotate pipeline (SSA renames, no copies)
      c0 = d0; c1 = d1; c2 = d2; c3 = d3;
      d0 = n0; d1 = n1; d2 = n2; d3 = n3;
    }
  }

  // hoisted issue: layer-2 eps prologue (pass 0) — survives lgkm-only barrier
  const int lane2 = g * 64 + l16;  // f4 units
  const float4* ep2 = (const float4*)(eps_w2 + (size_t)b * H2 * H1) + lane2;
  float4 fA[8];
  #pragma unroll
  for (int c = 0; c < 4; ++c) {
    fA[c]     = ep2[c * 16];
    fA[4 + c] = ep2[1024 + c * 16];
  }

  bar_lgkm();

  // ---- phase 4: layer 2 — 2 rows/group/pass, depth-1 eps prefetch ----
  {
    const float4* tp = (const float4*)(tabs + P2F) + 2 * lane2;

    float4 fB[8];
    #pragma unroll
    for (int p = 0; p < 4; ++p) {
      const int B0 = p * 2048;
      const int C = 2 * B0;
      float4 cf[8];
      #pragma unroll
      for (int c = 0; c < 8; ++c) cf[c] = (p & 1) ? fB[c] : fA[c];
      if (p < 3) {
        #pragma unroll
        for (int c = 0; c < 4; ++c) {
          if (p & 1) {
            fA[c]     = ep2[B0 + 2048 + c * 16];
            fA[4 + c] = ep2[B0 + 3072 + c * 16];
          } else {
            fB[c]     = ep2[B0 + 2048 + c * 16];
            fB[4 + c] = ep2[B0 + 3072 + c * 16];
          }
        }
      }
      float a0[SN] = {0.f, 0.f, 0.f, 0.f, 0.f};
      float a1[SN] = {0.f, 0.f, 0.f, 0.f, 0.f};
      #pragma unroll
      for (int c = 0; c < 4; ++c) {
        float4 m0 = tp[C + c * 32],        s0 = tp[C + c * 32 + 1];
        float4 m1 = tp[C + 2048 + c * 32], s1 = tp[C + 2048 + c * 32 + 1];
        float4 w0 = exp2m4_(m0, s0, cf[c]);
        float4 w1 = exp2m4_(m1, s1, cf[4 + c]);
        #pragma unroll
        for (int s2 = 0; s2 < SN; ++s2) {
          float4 h = *(const float4*)&h1s[s2][c * 64 + l16 * 4];
          a0[s2] += dot4_(w0, h);
          a1[s2] += dot4_(w1, h);
        }
      }
      float red[SN];
      #pragma unroll
      for (int s2 = 0; s2 < SN; ++s2) {
        float u0 = __shfl_xor(a0[s2], 8);
        float u1 = __shfl_xor(a1[s2], 8);
        float a = (l16 < 8) ? (a0[s2] + u0) : (a1[s2] + u1);
        a += __shfl_xor(a, 4);
        a += __shfl_xor(a, 2);
        a += __shfl_xor(a, 1);
        red[s2] = a;
      }
      const int o0 = p * 32 + g, o1 = o0 + 16;
      if (l16 == 0) {
        #pragma unroll
        for (int s2 = 0; s2 < SN; ++s2) h2s[s2][o0] = tanh_fast(red[s2] + bias2[o0]);
      } else if (l16 == 8) {
        #pragma unroll
        for (int s2 = 0; s2 < SN; ++s2) h2s[s2][o1] = tanh_fast(red[s2] + bias2[o1]);
      }
    }
  }
  bar_lgkm();

  // ---- phase 5: layer 3 + sigmoid, wave 0 only ----
  if (t < 64) {
    float w3a = w3v[t];
    float w3b = w3v[t + 64];
    float part[SN];
    #pragma unroll
    for (int s2 = 0; s2 < SN; ++s2) part[s2] = w3a * h2s[s2][t] + w3b * h2s[s2][t + 64];
    #pragma unroll
    for (int off = 32; off >= 1; off >>= 1) {
      #pragma unroll
      for (int s2 = 0; s2 < SN; ++s2) part[s2] += __shfl_xor(part[s2], off);
    }
    if (t == 0) {
      float bb3 = b_mu3[0] + tabs[SB3F] * eps_b3[b];
      #pragma unroll
      for (int s2 = 0; s2 < SN; ++s2) out[(size_t)s2 * BB + b] = sig_(part[s2] + bb3);
    }
  }
}

extern "C" void kernel_launch(void* const* d_in, const int* in_sizes, int n_in,
                              void* d_out, int out_size, void* d_ws, size_t ws_size,
                              hipStream_t stream) {
  const int*   stu_id      = (const int*)  d_in[0];
  const int*   exer_id     = (const int*)  d_in[1];
  const float* kn_r        = (const float*)d_in[2];
  const float* stu_cnt     = (const float*)d_in[3];
  const float* exer_cnt    = (const float*)d_in[4];
  const float* s_emb       = (const float*)d_in[5];
  const float* e_emb       = (const float*)d_in[6];
  const float* k_emb       = (const float*)d_in[7];
  const float* e_disc_mean = (const float*)d_in[8];
  const float* e_disc_eta  = (const float*)d_in[9];
  const float* w_sm        = (const float*)d_in[10];
  const float* b_sm        = (const float*)d_in[11];
  const float* w_ss        = (const float*)d_in[12];
  const float* b_ss        = (const float*)d_in[13];
  const float* w_km        = (const float*)d_in[14];
  const float* b_km        = (const float*)d_in[15];
  const float* w_ks        = (const float*)d_in[16];
  const float* b_ks        = (const float*)d_in[17];
  const float* lam1s       = (const float*)d_in[18];
  const float* lam2s       = (const float*)d_in[19];
  const float* lam1e       = (const float*)d_in[20];
  const float* lam2e       = (const float*)d_in[21];
  const float* w_mu1       = (const float*)d_in[22];
  const float* eta_w1      = (const float*)d_in[23];
  const float* b_mu1       = (const float*)d_in[24];
  const float* eta_b1      = (const float*)d_in[25];
  const float* w_mu2       = (const float*)d_in[26];
  const float* eta_w2      = (const float*)d_in[27];
  const float* b_mu2       = (const float*)d_in[28];
  const float* eta_b2      = (const float*)d_in[29];
  const float* w_mu3       = (const float*)d_in[30];
  const float* eta_w3      = (const float*)d_in[31];
  const float* b_mu3       = (const float*)d_in[32];
  const float* eta_b3      = (const float*)d_in[33];
  const float* eps_stat    = (const float*)d_in[34];
  const float* eps_kdiff   = (const float*)d_in[35];
  const float* eps_disc    = (const float*)d_in[36];
  const float* eps_w1      = (const float*)d_in[37];
  const float* eps_b1      = (const float*)d_in[38];
  const float* eps_w2      = (const float*)d_in[39];
  const float* eps_b2      = (const float*)d_in[40];
  const float* eps_w3      = (const float*)d_in[41];
  const float* eps_b3      = (const float*)d_in[42];

  float* out = (float*)d_out;
  float* ws  = (float*)d_ws;

  hipMemsetAsync((char*)d_out + (size_t)SN * BB * sizeof(float), 0, sizeof(float), stream);

  prep_kl<<<(N_STD + 255) / 256, 256, 0, stream>>>(
      w_mu1, eta_w1, b_mu1, eta_b1,
      w_mu2, eta_w2, b_mu2, eta_b2,
      w_mu3, eta_w3, b_mu3, eta_b3,
      ws, out + (size_t)SN * BB);

  bayes_main<<<BB, 256, 0, stream>>>(
      stu_id, exer_id, kn_r, stu_cnt, exer_cnt,
      s_emb, e_emb, k_emb, e_disc_mean, e_disc_eta,
      w_sm, b_sm, w_ss, b_ss, w_km, b_km, w_ks, b_ks,
      lam1s, lam2s, lam1e, lam2e,
      b_mu1, b_mu2, b_mu3,
      eps_stat, eps_kdiff, eps_disc,
      eps_w1, eps_b1, eps_w2, eps_b2, eps_w3, eps_b3,
      ws, out);
}